// Round 1
// baseline (441.744 us; speedup 1.0000x reference)
//
#include <hip/hip_runtime.h>
#include <stdint.h>

#define E 8192
#define KACT 164          // ceil(0.02 * 8192)
#define TPB 256
#define SKEW(i) ((i) + ((i) >> 5))

// ---------------- ws layout: [0]=max bits (uint, >=0 float), [1]=winner count
__global__ void init_ws_kernel(unsigned int* ws) {
    ws[0] = 0u;
    ws[1] = 0u;
}

// ---------------- global max(0, max(tensor)) -> ws[0] as uint bits
__global__ void __launch_bounds__(TPB) gmax_kernel(const float* __restrict__ T,
                                                   unsigned int* __restrict__ ws,
                                                   int n4) {
    int tid = blockIdx.x * blockDim.x + threadIdx.x;
    int stride = gridDim.x * blockDim.x;
    const float4* T4 = (const float4*)T;
    float m = 0.0f;  // clamp at 0 built in
    for (int i = tid; i < n4; i += stride) {
        float4 v = T4[i];
        m = fmaxf(m, fmaxf(fmaxf(v.x, v.y), fmaxf(v.z, v.w)));
    }
    for (int d = 32; d >= 1; d >>= 1) m = fmaxf(m, __shfl_xor(m, d, 64));
    if ((threadIdx.x & 63) == 0) atomicMax(&ws[0], __float_as_uint(m));
}

// ---------------- per-row top-k select + outputs
// MODE 0: normal pass. MODE 1: all-zero fallback (out = mask), runs only if count==0.
template <int MODE>
__global__ void __launch_bounds__(TPB) select_kernel(
    const float* __restrict__ T, const float* __restrict__ BT,
    const float* __restrict__ BP, const unsigned int* __restrict__ ws_max,
    float* __restrict__ out, float* __restrict__ boost_out,
    unsigned int* __restrict__ count) {

    __shared__ unsigned int keys[SKEW(E - 1) + 1 + 4];  // 8192 + skew pad
    __shared__ unsigned int hist[256];
    __shared__ unsigned int sgn[E / 32];
    __shared__ unsigned int actEq[E / 32];
    __shared__ unsigned int s_bin, s_kk;
    __shared__ int waveSum[4];

    if (MODE == 1) {
        if (count[0] != 0u) return;  // uniform: fallback not needed
    }

    const int t = threadIdx.x;
    const int row = blockIdx.x;
    const size_t base = (size_t)row * E;
    const int lane = t & 63;
    const int wid = t >> 6;

    const float c = __uint_as_float(ws_max[0]) * BP[0];

    sgn[t] = 0u;
    __syncthreads();

    const float4* T4 = (const float4*)(T + base);
    const float4* BT4 = (const float4*)(BT + base);
    float4* BO4 = (float4*)(boost_out + base);

    // ---- load pass: keys to LDS, stream boost_out, sign nibbles
    for (int j = 0; j < E / 4 / TPB; ++j) {  // 8 iters
        int u = j * TPB + t;                 // float4 index
        float4 tv = T4[u];
        float4 bv = BT4[u];
        float tvv[4] = {tv.x, tv.y, tv.z, tv.w};
        float bvv[4] = {bv.x, bv.y, bv.z, bv.w};
        unsigned int nib = 0u;
#pragma unroll
        for (int i = 0; i < 4; ++i) {
            float b = bvv[i] + c;
            float x = tvv[i];
            float boosted = (x > 0.0f ? x : 0.0f) + b;
            unsigned int s = __float_as_uint(boosted);
            unsigned int key = (s & 0x80000000u) ? ~s : (s | 0x80000000u);
            keys[SKEW(4 * u + i)] = key;
            if (x > 0.0f) nib |= (1u << i);
            bvv[i] = b;
        }
        if (MODE == 0) {
            float4 bo = {bvv[0], bvv[1], bvv[2], bvv[3]};
            BO4[u] = bo;
            atomicOr(&sgn[u >> 3], nib << ((u & 7) * 4));
        }
    }
    __syncthreads();

    // ---- radix select: find KACT-th largest key (exact) ----
    unsigned int prefix = 0u;
    int kk = KACT;
    for (int level = 0; level < 4; ++level) {
        const int shift = 24 - 8 * level;
        hist[t] = 0u;
        __syncthreads();
        for (int j = 0; j < E / TPB; ++j) {  // 32 iters
            unsigned int key = keys[SKEW(j * TPB + t)];
            bool match = (level == 0) || ((key >> (shift + 8)) == prefix);
            if (match) atomicAdd(&hist[(key >> shift) & 255u], 1u);
        }
        __syncthreads();
        if (t == 0) {
            unsigned int cum = 0u;
            int b = 255;
            for (; b >= 0; --b) {
                cum += hist[b];
                if (cum >= (unsigned int)kk) break;
            }
            s_bin = (unsigned int)b;
            s_kk = (unsigned int)kk - (cum - hist[b]);
        }
        __syncthreads();
        prefix = (prefix << 8) | s_bin;
        kk = (int)s_kk;
        __syncthreads();
    }
    const unsigned int Kth = prefix;  // exact k-th largest key
    const int nEq = kk;               // #equal keys to keep (lowest index first)

    // ---- tie-break: rank equal keys by index (chunked scan) ----
    int cnt = 0;
#pragma unroll
    for (int i = 0; i < 32; ++i) cnt += (keys[SKEW(32 * t + i)] == Kth) ? 1 : 0;
    int v = cnt;
    for (int d = 1; d < 64; d <<= 1) {
        int n = __shfl_up(v, d, 64);
        if (lane >= d) v += n;
    }
    if (lane == 63) waveSum[wid] = v;
    __syncthreads();
    int off = 0;
    for (int w = 0; w < wid; ++w) off += waveSum[w];
    int rank = off + v - cnt;  // exclusive prefix of equal-count by index
    unsigned int bits = 0u;
#pragma unroll
    for (int i = 0; i < 32; ++i) {
        if (keys[SKEW(32 * t + i)] == Kth) {
            if (rank < nEq) bits |= (1u << i);
            ++rank;
        }
    }
    actEq[t] = bits;
    __syncthreads();

    // ---- output pass ----
    float4* O4 = (float4*)(out + base);
    unsigned int cntAct = 0u;
    for (int j = 0; j < E / 4 / TPB; ++j) {  // 8 iters
        int u = j * TPB + t;
        unsigned int sg = sgn[u >> 3] >> ((u & 7) * 4);
        float o[4];
#pragma unroll
        for (int i = 0; i < 4; ++i) {
            int e = 4 * u + i;
            unsigned int key = keys[SKEW(e)];
            bool act = (key > Kth) ||
                       (key == Kth && ((actEq[e >> 5] >> (e & 31)) & 1u));
            if (MODE == 0) {
                bool sb = (sg >> i) & 1u;
                bool on = act && sb;
                o[i] = on ? 1.0f : 0.0f;
                cntAct += on ? 1u : 0u;
                if (act) boost_out[base + e] = 0.0f;  // same thread wrote it above
            } else {
                o[i] = act ? 1.0f : 0.0f;
            }
        }
        float4 ov = {o[0], o[1], o[2], o[3]};
        O4[u] = ov;
    }
    if (MODE == 0) {
        for (int d = 32; d >= 1; d >>= 1) cntAct += __shfl_xor(cntAct, d, 64);
        if (lane == 0) atomicAdd(count, cntAct);
    }
}

extern "C" void kernel_launch(void* const* d_in, const int* in_sizes, int n_in,
                              void* d_out, int out_size, void* d_ws, size_t ws_size,
                              hipStream_t stream) {
    const float* T = (const float*)d_in[0];
    const float* BT = (const float*)d_in[1];
    const float* BP = (const float*)d_in[2];
    const int B = in_sizes[0] / E;  // 4096
    float* out = (float*)d_out;
    float* boost_out = out + (size_t)B * E;
    unsigned int* ws = (unsigned int*)d_ws;

    hipLaunchKernelGGL(init_ws_kernel, dim3(1), dim3(1), 0, stream, ws);

    const int n4 = in_sizes[0] / 4;
    hipLaunchKernelGGL(gmax_kernel, dim3(2048), dim3(TPB), 0, stream, T, ws, n4);

    hipLaunchKernelGGL((select_kernel<0>), dim3(B), dim3(TPB), 0, stream,
                       T, BT, BP, ws, out, boost_out, ws + 1);
    // all-zero fallback (general semantics); every block early-exits when count != 0
    hipLaunchKernelGGL((select_kernel<1>), dim3(B), dim3(TPB), 0, stream,
                       T, BT, BP, ws, out, boost_out, ws + 1);
}

// Round 2
// 302.798 us; speedup vs baseline: 1.4589x; 1.4589x over previous
//
#include <hip/hip_runtime.h>
#include <stdint.h>

#define E 8192
#define KACT 164          // ceil(0.02 * 8192)
#define TPB 256

// ---------------- ws layout: [0]=max bits (uint, >=0 float), [1]=winner count
__global__ void init_ws_kernel(unsigned int* ws) {
    ws[0] = 0u;
    ws[1] = 0u;
}

// ---------------- global max(0, max(tensor)) -> ws[0] as uint bits
__global__ void __launch_bounds__(TPB) gmax_kernel(const float* __restrict__ T,
                                                   unsigned int* __restrict__ ws,
                                                   int n4) {
    __shared__ float wmax[4];
    int tid = blockIdx.x * blockDim.x + threadIdx.x;
    int stride = gridDim.x * blockDim.x;
    const float4* T4 = (const float4*)T;
    float m = 0.0f;  // clamp at 0 built in
    for (int i = tid; i < n4; i += stride) {
        float4 v = T4[i];
        m = fmaxf(m, fmaxf(fmaxf(v.x, v.y), fmaxf(v.z, v.w)));
    }
    for (int d = 32; d >= 1; d >>= 1) m = fmaxf(m, __shfl_xor(m, d, 64));
    int lane = threadIdx.x & 63, wid = threadIdx.x >> 6;
    if (lane == 0) wmax[wid] = m;
    __syncthreads();
    if (threadIdx.x == 0) {
        m = fmaxf(fmaxf(wmax[0], wmax[1]), fmaxf(wmax[2], wmax[3]));
        atomicMax(ws, __float_as_uint(m));  // valid: m >= 0 -> uint bits monotone
    }
}

// ---------------- per-row top-k select + outputs, keys register-resident
// Thread t owns elements e = 4*(j*TPB+t)+i for j=0..7, i=0..3 (all loops unrolled).
// MODE 0: normal pass. MODE 1: all-zero fallback (out = mask), runs only if count==0.
template <int MODE>
__global__ void __launch_bounds__(TPB) select_kernel(
    const float* __restrict__ T, const float* __restrict__ BT,
    const float* __restrict__ BP, const unsigned int* __restrict__ ws_max,
    float* __restrict__ out, float* __restrict__ boost_out,
    unsigned int* __restrict__ count) {

    __shared__ unsigned int hist[256];
    __shared__ unsigned int wt[4];
    __shared__ unsigned int s_bin, s_kk;
    __shared__ unsigned int cntJW[8 * 4];  // per-(j, wave) equal-counts

    if (MODE == 1) {
        if (count[0] != 0u) return;  // uniform: fallback not needed
    }

    const int t = threadIdx.x;
    const int lane = t & 63;
    const int wid = t >> 6;
    const size_t base = (size_t)blockIdx.x * E;

    const float c = __uint_as_float(ws_max[0]) * BP[0];

    const float4* T4 = (const float4*)(T + base);
    const float4* BT4 = (const float4*)(BT + base);
    float4* BO4 = (float4*)(boost_out + base);

    unsigned int keys[32];
    unsigned int m_sg = 0u;  // x>0 bitmask over 32 owned elements

    // ---- load pass: keys to registers, stream boost_out
#pragma unroll
    for (int j = 0; j < 8; ++j) {
        int u = j * TPB + t;  // float4 index
        float4 tv = T4[u];
        float4 bv = BT4[u];
        float xs[4] = {tv.x, tv.y, tv.z, tv.w};
        float bs[4] = {bv.x, bv.y, bv.z, bv.w};
        float bo[4];
#pragma unroll
        for (int i = 0; i < 4; ++i) {
            float b = bs[i] + c;
            float x = xs[i];
            float boosted = (x > 0.0f ? x : 0.0f) + b;
            unsigned int s = __float_as_uint(boosted);
            keys[j * 4 + i] = (s & 0x80000000u) ? ~s : (s | 0x80000000u);
            if (x > 0.0f) m_sg |= (1u << (j * 4 + i));
            bo[i] = b;
        }
        if (MODE == 0) {
            float4 o = {bo[0], bo[1], bo[2], bo[3]};
            BO4[u] = o;
        }
    }

    // ---- radix select on register keys: find KACT-th largest key (exact)
    unsigned int prefix = 0u;
    unsigned int kk = KACT;
#pragma unroll
    for (int level = 0; level < 4; ++level) {
        const int shift = 24 - 8 * level;
        hist[t] = 0u;
        __syncthreads();
#pragma unroll
        for (int s = 0; s < 32; ++s) {
            unsigned int key = keys[s];
            bool match = (level == 0) || ((key >> (shift + 8)) == prefix);
            if (match) atomicAdd(&hist[(key >> shift) & 255u], 1u);
        }
        __syncthreads();
        unsigned int h = hist[t];
        // wave-level inclusive suffix scan over this wave's 64 bins
        unsigned int v = h;
#pragma unroll
        for (int d = 1; d < 64; d <<= 1) {
            unsigned int x = __shfl_down(v, d, 64);
            if (lane + d < 64) v += x;
        }
        if (lane == 0) wt[wid] = v;  // wave total
        __syncthreads();
        unsigned int S = v;  // suffix sum from bin t upward
        for (int w = wid + 1; w < 4; ++w) S += wt[w];
        if (S >= kk && (S - h) < kk) {  // unique largest bin with cum >= kk
            s_bin = (unsigned int)t;
            s_kk = kk - (S - h);
        }
        __syncthreads();
        prefix = (prefix << 8) | s_bin;
        kk = s_kk;
    }
    const unsigned int Kth = prefix;  // exact k-th largest key
    const unsigned int nEq = kk;      // #equal keys to keep (lowest index first)

    // ---- exact tie-break rank via ballots (index order e = 1024j + 4t + i)
    unsigned int m_eq = 0u, m_gt = 0u;
#pragma unroll
    for (int s = 0; s < 32; ++s) {
        unsigned int k = keys[s];
        if (k == Kth) m_eq |= (1u << s);
        if (k > Kth) m_gt |= (1u << s);
    }

#pragma unroll
    for (int j = 0; j < 8; ++j) {
        unsigned int tot = 0u;
#pragma unroll
        for (int i = 0; i < 4; ++i) {
            unsigned long long bal = __ballot((m_eq >> (j * 4 + i)) & 1u);
            tot += (unsigned int)__popcll(bal);
        }
        if (lane == 0) cntJW[j * 4 + wid] = tot;
    }
    __syncthreads();

    unsigned int R[8];  // rank base per j for this thread
    {
        const unsigned long long lt = (1ull << lane) - 1ull;
        unsigned int A = 0u;  // total equals in rows j' < j
#pragma unroll
        for (int j = 0; j < 8; ++j) {
            unsigned int Wlt = 0u, rowTot = 0u;
#pragma unroll
            for (int w = 0; w < 4; ++w) {
                unsigned int cw = cntJW[j * 4 + w];
                rowTot += cw;
                if (w < wid) Wlt += cw;
            }
            unsigned int P = 0u;
#pragma unroll
            for (int i = 0; i < 4; ++i) {
                unsigned long long bal = __ballot((m_eq >> (j * 4 + i)) & 1u);
                P += (unsigned int)__popcll(bal & lt);
            }
            R[j] = A + Wlt + P;
            A += rowTot;
        }
    }

    // ---- output pass
    float4* O4 = (float4*)(out + base);
    unsigned int cntAct = 0u;
#pragma unroll
    for (int j = 0; j < 8; ++j) {
        int u = j * TPB + t;
        float o[4];
        unsigned int ownlower = 0u;
#pragma unroll
        for (int i = 0; i < 4; ++i) {
            int s = j * 4 + i;
            bool eq = (m_eq >> s) & 1u;
            bool act = ((m_gt >> s) & 1u) != 0u;
            if (eq) {
                unsigned int rank = R[j] + ownlower;
                if (rank < nEq) act = true;
                ++ownlower;
            }
            if (MODE == 0) {
                bool on = act && (((m_sg >> s) & 1u) != 0u);
                o[i] = on ? 1.0f : 0.0f;
                cntAct += on ? 1u : 0u;
                if (act) boost_out[base + (size_t)(4 * u + i)] = 0.0f;
            } else {
                o[i] = act ? 1.0f : 0.0f;
            }
        }
        float4 ov = {o[0], o[1], o[2], o[3]};
        O4[u] = ov;
    }
    if (MODE == 0) {
        for (int d = 32; d >= 1; d >>= 1) cntAct += __shfl_xor(cntAct, d, 64);
        if (lane == 0) atomicAdd(count, cntAct);
    }
}

extern "C" void kernel_launch(void* const* d_in, const int* in_sizes, int n_in,
                              void* d_out, int out_size, void* d_ws, size_t ws_size,
                              hipStream_t stream) {
    const float* T = (const float*)d_in[0];
    const float* BT = (const float*)d_in[1];
    const float* BP = (const float*)d_in[2];
    const int B = in_sizes[0] / E;  // 4096
    float* out = (float*)d_out;
    float* boost_out = out + (size_t)B * E;
    unsigned int* ws = (unsigned int*)d_ws;

    hipLaunchKernelGGL(init_ws_kernel, dim3(1), dim3(1), 0, stream, ws);

    const int n4 = in_sizes[0] / 4;
    hipLaunchKernelGGL(gmax_kernel, dim3(4096), dim3(TPB), 0, stream, T, ws, n4);

    hipLaunchKernelGGL((select_kernel<0>), dim3(B), dim3(TPB), 0, stream,
                       T, BT, BP, ws, out, boost_out, ws + 1);
    // all-zero fallback (general semantics); every block early-exits when count != 0
    hipLaunchKernelGGL((select_kernel<1>), dim3(B), dim3(TPB), 0, stream,
                       T, BT, BP, ws, out, boost_out, ws + 1);
}

// Round 3
// 197.559 us; speedup vs baseline: 2.2360x; 1.5327x over previous
//
#include <hip/hip_runtime.h>
#include <stdint.h>

#define E 8192
#define KACT 164           // ceil(0.02 * 8192)
#define TPR 256            // threads per row
#define RPB 2              // rows per block
#define TPB (TPR * RPB)    // 512

// ---------------- ws layout: [0]=max bits (uint, >=0 float), [1]=winner count
__global__ void init_ws_kernel(unsigned int* ws) {
    ws[0] = 0u;
    ws[1] = 0u;
}

// ---------------- global max(0, max(tensor)) -> ws[0] as uint bits
__global__ void __launch_bounds__(256) gmax_kernel(const float* __restrict__ T,
                                                   unsigned int* __restrict__ ws,
                                                   int n4) {
    __shared__ float wmax[4];
    int tid = blockIdx.x * 256 + threadIdx.x;
    int stride = gridDim.x * 256;
    const float4* T4 = (const float4*)T;
    float m = 0.0f;  // clamp at 0 built in
    for (int i = tid; i < n4; i += stride) {
        float4 v = T4[i];
        m = fmaxf(m, fmaxf(fmaxf(v.x, v.y), fmaxf(v.z, v.w)));
    }
    for (int d = 32; d >= 1; d >>= 1) m = fmaxf(m, __shfl_xor(m, d, 64));
    int lane = threadIdx.x & 63, wid = threadIdx.x >> 6;
    if (lane == 0) wmax[wid] = m;
    __syncthreads();
    if (threadIdx.x == 0) {
        m = fmaxf(fmaxf(wmax[0], wmax[1]), fmaxf(wmax[2], wmax[3]));
        atomicMax(ws, __float_as_uint(m));
    }
}

// ---------------- per-row top-k select + outputs, 2 rows per 512-thread block
// Row r = t>>8 handled by threads [r*256, r*256+255]; thread owns elements
// e = 4*(j*256 + (t&255)) + i for j=0..7, i=0..3 (keys register-resident).
// MODE 0: normal pass. MODE 1: all-zero fallback (out = mask), runs only if count==0.
template <int MODE>
__global__ void __launch_bounds__(TPB, 4) select_kernel(
    const float* __restrict__ T, const float* __restrict__ BT,
    const float* __restrict__ BP, const unsigned int* __restrict__ ws_max,
    float* __restrict__ out, float* __restrict__ boost_out,
    unsigned int* __restrict__ count, int Btot) {

    __shared__ unsigned int hist[RPB][256];
    __shared__ unsigned int wt[RPB][4];
    __shared__ unsigned int s_bin[RPB], s_kk[RPB];
    __shared__ unsigned int cntJW[RPB][8][4];
    __shared__ unsigned int scnt;

    if (MODE == 1) {
        if (count[0] != 0u) return;  // uniform: fallback not needed
    }

    const int t = threadIdx.x;
    const int r = t >> 8;           // row within block
    const int tr = t & (TPR - 1);   // thread within row
    const int lane = t & 63;
    const int wrow = (t >> 6) & 3;  // wave within row group
    int row = blockIdx.x * RPB + r;
    const bool rowValid = (row < Btot);
    if (!rowValid) row = Btot - 1;  // safe addresses; stores predicated
    const size_t base = (size_t)row * E;

    if (t == 0) scnt = 0u;

    const float c = __uint_as_float(ws_max[0]) * BP[0];

    const float4* T4 = (const float4*)(T + base);
    const float4* BT4 = (const float4*)(BT + base);

    unsigned int keys[32];
    unsigned int m_sg = 0u;  // x>0 bitmask over 32 owned elements

    // ---- load pass: keys to registers (pure read, no stores)
#pragma unroll
    for (int j = 0; j < 8; ++j) {
        int u = j * TPR + tr;  // float4 index within row
        float4 tv = T4[u];
        float4 bv = BT4[u];
        float xs[4] = {tv.x, tv.y, tv.z, tv.w};
        float bs[4] = {bv.x, bv.y, bv.z, bv.w};
#pragma unroll
        for (int i = 0; i < 4; ++i) {
            float b = bs[i] + c;
            float x = xs[i];
            float boosted = (x > 0.0f ? x : 0.0f) + b;
            unsigned int s = __float_as_uint(boosted);
            keys[j * 4 + i] = (s & 0x80000000u) ? ~s : (s | 0x80000000u);
            if (x > 0.0f) m_sg |= (1u << (j * 4 + i));
        }
    }

    // ---- radix select on register keys: find KACT-th largest key (exact)
    unsigned int prefix = 0u;
    unsigned int kk = KACT;
#pragma unroll
    for (int level = 0; level < 4; ++level) {
        const int shift = 24 - 8 * level;
        hist[r][tr] = 0u;
        __syncthreads();
#pragma unroll
        for (int s = 0; s < 32; ++s) {
            unsigned int key = keys[s];
            bool match = (level == 0) || ((key >> (shift + 8)) == prefix);
            if (match) atomicAdd(&hist[r][(key >> shift) & 255u], 1u);
        }
        __syncthreads();
        unsigned int h = hist[r][tr];
        // inclusive suffix scan within this wave's 64 bins
        unsigned int v = h;
#pragma unroll
        for (int d = 1; d < 64; d <<= 1) {
            unsigned int x = __shfl_down(v, d, 64);
            if (lane + d < 64) v += x;
        }
        if (lane == 0) wt[r][wrow] = v;
        __syncthreads();
        unsigned int S = v;  // suffix sum from bin tr upward (within row)
        for (int w = wrow + 1; w < 4; ++w) S += wt[r][w];
        if (S >= kk && (S - h) < kk) {  // unique bin holding the kk-th key
            s_bin[r] = (unsigned int)tr;
            s_kk[r] = kk - (S - h);
        }
        __syncthreads();
        prefix = (prefix << 8) | s_bin[r];
        kk = s_kk[r];
    }
    const unsigned int Kth = prefix;  // exact k-th largest key
    const unsigned int nEq = kk;      // #equal keys to keep (lowest index first)

    // ---- exact tie-break rank via ballots (index order e = 1024j + 4tr + i)
    unsigned int m_eq = 0u, m_gt = 0u;
#pragma unroll
    for (int s = 0; s < 32; ++s) {
        unsigned int k = keys[s];
        if (k == Kth) m_eq |= (1u << s);
        if (k > Kth) m_gt |= (1u << s);
    }

#pragma unroll
    for (int j = 0; j < 8; ++j) {
        unsigned int tot = 0u;
#pragma unroll
        for (int i = 0; i < 4; ++i) {
            unsigned long long bal = __ballot((m_eq >> (j * 4 + i)) & 1u);
            tot += (unsigned int)__popcll(bal);
        }
        if (lane == 0) cntJW[r][j][wrow] = tot;
    }
    __syncthreads();

    unsigned int R[8];  // rank base per j for this thread
    {
        const unsigned long long lt = (1ull << lane) - 1ull;
        unsigned int A = 0u;  // total equals in chunks j' < j (this row)
#pragma unroll
        for (int j = 0; j < 8; ++j) {
            unsigned int Wlt = 0u, rowTot = 0u;
#pragma unroll
            for (int w = 0; w < 4; ++w) {
                unsigned int cw = cntJW[r][j][w];
                rowTot += cw;
                if (w < wrow) Wlt += cw;
            }
            unsigned int P = 0u;
#pragma unroll
            for (int i = 0; i < 4; ++i) {
                unsigned long long bal = __ballot((m_eq >> (j * 4 + i)) & 1u);
                P += (unsigned int)__popcll(bal & lt);
            }
            R[j] = A + Wlt + P;
            A += rowTot;
        }
    }

    // ---- output pass: clean float4 streams, boost zeros merged
    float4* O4 = (float4*)(out + base);
    float4* BO4 = (float4*)(boost_out + base);
    unsigned int cntAct = 0u;
#pragma unroll
    for (int j = 0; j < 8; ++j) {
        int u = j * TPR + tr;
        float o[4], bo[4];
        float4 bv;
        if (MODE == 0) bv = BT4[u];  // re-read (L2/L3-hot)
        float bs[4] = {bv.x, bv.y, bv.z, bv.w};
        unsigned int ownlower = 0u;
#pragma unroll
        for (int i = 0; i < 4; ++i) {
            int s = j * 4 + i;
            bool eq = (m_eq >> s) & 1u;
            bool act = ((m_gt >> s) & 1u) != 0u;
            if (eq) {
                unsigned int rank = R[j] + ownlower;
                if (rank < nEq) act = true;
                ++ownlower;
            }
            if (MODE == 0) {
                bool on = act && (((m_sg >> s) & 1u) != 0u);
                o[i] = on ? 1.0f : 0.0f;
                cntAct += on ? 1u : 0u;
                bo[i] = act ? 0.0f : (bs[i] + c);
            } else {
                o[i] = act ? 1.0f : 0.0f;
            }
        }
        if (rowValid) {
            float4 ov = {o[0], o[1], o[2], o[3]};
            O4[u] = ov;
            if (MODE == 0) {
                float4 bov = {bo[0], bo[1], bo[2], bo[3]};
                BO4[u] = bov;
            }
        }
    }
    if (MODE == 0) {
        for (int d = 32; d >= 1; d >>= 1) cntAct += __shfl_xor(cntAct, d, 64);
        if (lane == 0 && rowValid) atomicAdd(&scnt, cntAct);
        __syncthreads();
        if (t == 0) atomicAdd(count, scnt);
    }
}

extern "C" void kernel_launch(void* const* d_in, const int* in_sizes, int n_in,
                              void* d_out, int out_size, void* d_ws, size_t ws_size,
                              hipStream_t stream) {
    const float* T = (const float*)d_in[0];
    const float* BT = (const float*)d_in[1];
    const float* BP = (const float*)d_in[2];
    const int B = in_sizes[0] / E;  // 4096
    float* out = (float*)d_out;
    float* boost_out = out + (size_t)B * E;
    unsigned int* ws = (unsigned int*)d_ws;

    hipLaunchKernelGGL(init_ws_kernel, dim3(1), dim3(1), 0, stream, ws);

    const int n4 = in_sizes[0] / 4;
    hipLaunchKernelGGL(gmax_kernel, dim3(1024), dim3(256), 0, stream, T, ws, n4);

    const int nblk = (B + RPB - 1) / RPB;
    hipLaunchKernelGGL((select_kernel<0>), dim3(nblk), dim3(TPB), 0, stream,
                       T, BT, BP, ws, out, boost_out, ws + 1, B);
    // all-zero fallback (general semantics); every block early-exits when count != 0
    hipLaunchKernelGGL((select_kernel<1>), dim3(nblk), dim3(TPB), 0, stream,
                       T, BT, BP, ws, out, boost_out, ws + 1, B);
}